// Round 3
// baseline (611.850 us; speedup 1.0000x reference)
//
#include <hip/hip_runtime.h>
#include <hip/hip_bf16.h>

#define N_NODES 100000
#define N_EDGES 1250000
#define DIM 64
#define NB 782            // ceil(100000/128) buckets of 128 nodes
#define NCHUNK 128
#define CHUNK 9766        // ceil(1250000/128)
#define MAX_STAGE 2560

typedef __attribute__((ext_vector_type(8))) short short8;
typedef __attribute__((ext_vector_type(8))) __bf16 bf16x8;
typedef __attribute__((ext_vector_type(4))) float f32x4;

static __device__ __forceinline__ short f2bf(float f) {
    union { float f; unsigned u; } v; v.f = f;
    unsigned r = (v.u + 0x7fffu + ((v.u >> 16) & 1u)) >> 16;
    return (short)r;
}
static __device__ __forceinline__ float bfu2f(unsigned u) {
    union { unsigned u; float f; } v; v.u = u << 16; return v.f;
}

// ---------------- W fragment prep ----------------
__global__ __launch_bounds__(256) void prep_w(const float* __restrict__ W1,
                                              const float* __restrict__ W2,
                                              short* __restrict__ wf) {
    int idx = blockIdx.x * 256 + threadIdx.x;   // 0..8191
    int layer = idx >> 12;
    int fi = idx & 4095;
    int fragidx = fi >> 9;
    int lane = (fi >> 3) & 63;
    int jj = fi & 7;
    int ct = fragidx >> 1, kt = fragidx & 1;
    int k = kt * 32 + (lane >> 4) * 8 + jj;
    int j = ct * 16 + (lane & 15);
    const float* W = layer ? W2 : W1;
    wf[idx] = f2bf(W[k * DIM + j]);
}

// ---------------- feat f32 -> bf16 ----------------
__global__ __launch_bounds__(256) void conv_feat(const float* __restrict__ f,
                                                 short* __restrict__ o) {
    int i = (blockIdx.x * 256 + threadIdx.x) * 8;   // grid exact: 6400000/8/256=3125
    float4 a = *(const float4*)(f + i);
    float4 b = *(const float4*)(f + i + 4);
    short8 t;
    t[0] = f2bf(a.x); t[1] = f2bf(a.y); t[2] = f2bf(a.z); t[3] = f2bf(a.w);
    t[4] = f2bf(b.x); t[5] = f2bf(b.y); t[6] = f2bf(b.z); t[7] = f2bf(b.w);
    *(short8*)(o + i) = t;
}

// ---------------- bucket partition ----------------
__global__ __launch_bounds__(256) void hist_chunks(const int* __restrict__ dst,
                                                   int* __restrict__ hist) {
    __shared__ int cnt[NB];
    for (int b = threadIdx.x; b < NB; b += 256) cnt[b] = 0;
    __syncthreads();
    int c = blockIdx.x;
    int base = c * CHUNK;
    int end = base + CHUNK; if (end > N_EDGES) end = N_EDGES;
    for (int i = base + threadIdx.x; i < end; i += 256)
        atomicAdd(&cnt[dst[i] >> 7], 1);
    __syncthreads();
    for (int b = threadIdx.x; b < NB; b += 256) hist[c * NB + b] = cnt[b];
}

// per-bucket running scan over chunks: hist[c][b] -> exclusive local offset; btot[b]=total
__global__ __launch_bounds__(64) void scan_cols(int* __restrict__ hist,
                                                int* __restrict__ btot) {
    int b = blockIdx.x * 64 + threadIdx.x;
    if (b >= NB) return;
    int run = 0;
    for (int c = 0; c < NCHUNK; ++c) {
        int t = hist[c * NB + b];
        hist[c * NB + b] = run;
        run += t;
    }
    btot[b] = run;
}

__global__ __launch_bounds__(1024) void scan_base(const int* __restrict__ btot,
                                                  int* __restrict__ bbase) {
    __shared__ int s[1024];
    int t = threadIdx.x;
    int v = (t < NB) ? btot[t] : 0;
    s[t] = v; __syncthreads();
    for (int off = 1; off < 1024; off <<= 1) {
        int u = (t >= off) ? s[t - off] : 0;
        __syncthreads();
        s[t] += u;
        __syncthreads();
    }
    if (t < NB) bbase[t] = s[t] - v;    // exclusive
}

// place edges: edgebuf[pos] = src | (dst&127)<<17, grouped by bucket
__global__ __launch_bounds__(256) void partition_edges(const int* __restrict__ src,
                                                       const int* __restrict__ dst,
                                                       const int* __restrict__ hist,
                                                       const int* __restrict__ bbase,
                                                       int* __restrict__ edgebuf) {
    __shared__ int cur[NB];
    int c = blockIdx.x;
    for (int b = threadIdx.x; b < NB; b += 256)
        cur[b] = bbase[b] + hist[c * NB + b];
    __syncthreads();
    int base = c * CHUNK;
    int end = base + CHUNK; if (end > N_EDGES) end = N_EDGES;
    for (int i = base + threadIdx.x; i < end; i += 256) {
        int d = dst[i];
        int b = d >> 7;
        int p = atomicAdd(&cur[b], 1);          // LDS return-atomic
        edgebuf[p] = src[i] | ((d & 127) << 17);
    }
}

// ---------------- per-bucket gather with LDS f32 accumulation ----------------
// BF=1: featp is bf16 (row 128B, lane reads uint=2 vals); BF=0: f32 (lane reads float2)
template<int BF>
__global__ __launch_bounds__(512) void bucket_gather(const int* __restrict__ bbase,
                                                     const int* __restrict__ btot,
                                                     const int* __restrict__ edgebuf,
                                                     const void* __restrict__ featp,
                                                     float* __restrict__ neigh) {
    __shared__ float tile[128][64];     // 32 KB
    __shared__ int ew[MAX_STAGE];       // 10 KB edge staging
    int b = blockIdx.x;
    int node0 = b << 7;
    int nn = N_NODES - node0; if (nn > 128) nn = 128;
    float* tf = &tile[0][0];
    for (int i = threadIdx.x; i < 128 * 64; i += 512) tf[i] = 0.f;
    int eb = bbase[b], ec = btot[b];
    int nst = ec < MAX_STAGE ? ec : MAX_STAGE;
    for (int i = threadIdx.x; i < nst; i += 512) ew[i] = edgebuf[eb + i];
    __syncthreads();

    int lane = threadIdx.x & 31;
    int sub = threadIdx.x >> 5;         // 0..15
    for (int it = 0; it < ec; it += 32) {
        int e0 = it + sub, e1 = it + 16 + sub;
        int w0 = (e0 < ec) ? (e0 < nst ? ew[e0] : edgebuf[eb + e0]) : -1;
        int w1 = (e1 < ec) ? (e1 < nst ? ew[e1] : edgebuf[eb + e1]) : -1;
        float f00 = 0.f, f01 = 0.f, f10 = 0.f, f11 = 0.f;
        if (BF) {
            const unsigned* fb = (const unsigned*)featp;
            unsigned p0 = 0, p1 = 0;
            if (w0 >= 0) p0 = fb[(w0 & 0x1FFFF) * 32 + lane];
            if (w1 >= 0) p1 = fb[(w1 & 0x1FFFF) * 32 + lane];
            f00 = bfu2f(p0 & 0xffffu); f01 = bfu2f(p0 >> 16);
            f10 = bfu2f(p1 & 0xffffu); f11 = bfu2f(p1 >> 16);
        } else {
            const float2* ff = (const float2*)featp;
            if (w0 >= 0) { float2 v = ff[(w0 & 0x1FFFF) * 32 + lane]; f00 = v.x; f01 = v.y; }
            if (w1 >= 0) { float2 v = ff[(w1 & 0x1FFFF) * 32 + lane]; f10 = v.x; f11 = v.y; }
        }
        if (w0 >= 0) {
            int d = (w0 >> 17) & 127;
            atomicAdd(&tile[d][lane * 2], f00);
            atomicAdd(&tile[d][lane * 2 + 1], f01);
        }
        if (w1 >= 0) {
            int d = (w1 >> 17) & 127;
            atomicAdd(&tile[d][lane * 2], f10);
            atomicAdd(&tile[d][lane * 2 + 1], f11);
        }
    }
    __syncthreads();
    for (int i = threadIdx.x; i < nn * 64; i += 512)
        neigh[(node0 << 6) + i] = tf[i];
}

// ---------------- fallback atomic scatter (tiny ws) ----------------
__global__ __launch_bounds__(256) void scatter_edges(const float4* __restrict__ feat4,
                                                     const int* __restrict__ src,
                                                     const int* __restrict__ dst,
                                                     float* __restrict__ neigh) {
    int idx = blockIdx.x * 256 + threadIdx.x;
    int e = idx >> 4, c = idx & 15;
    int s = src[e], d = dst[e];
    float4 v = feat4[s * 16 + c];
    float* p = neigh + d * 64 + c * 4;
    unsafeAtomicAdd(p + 0, v.x);
    unsafeAtomicAdd(p + 1, v.y);
    unsafeAtomicAdd(p + 2, v.z);
    unsafeAtomicAdd(p + 3, v.w);
}

// ---------------- fused combine + MLP ----------------
__global__ __launch_bounds__(256) void gin_mlp(const float* __restrict__ feat,
                                               float* __restrict__ neigh_out,
                                               const short* __restrict__ wf,
                                               const float* __restrict__ b1,
                                               const float* __restrict__ b2,
                                               const float* __restrict__ epsp) {
    __shared__ float hbuf[4][16][66];

    int lane = threadIdx.x & 63;
    int wv = threadIdx.x >> 6;
    int r = lane & 15, g = lane >> 4;
    int row0 = blockIdx.x * 64 + wv * 16;
    int node = row0 + r;
    bool valid = node < N_NODES;
    float epsv = 1.0f + epsp[0];

    const short8* w1f8 = (const short8*)(wf);
    const short8* w2f8 = (const short8*)(wf + 4096);

    short8 a[2];
    if (valid) {
        const float* fp = feat + node * 64 + g * 8;
        const float* np_ = neigh_out + node * 64 + g * 8;
#pragma unroll
        for (int kt = 0; kt < 2; ++kt) {
            float4 f0 = *(const float4*)(fp + kt * 32);
            float4 f1 = *(const float4*)(fp + kt * 32 + 4);
            float4 n0 = *(const float4*)(np_ + kt * 32);
            float4 n1 = *(const float4*)(np_ + kt * 32 + 4);
            float rs[8] = { epsv * f0.x + n0.x, epsv * f0.y + n0.y,
                            epsv * f0.z + n0.z, epsv * f0.w + n0.w,
                            epsv * f1.x + n1.x, epsv * f1.y + n1.y,
                            epsv * f1.z + n1.z, epsv * f1.w + n1.w };
            short8 t;
#pragma unroll
            for (int jj = 0; jj < 8; ++jj) t[jj] = f2bf(rs[jj]);
            a[kt] = t;
        }
    } else {
        short8 z = { 0, 0, 0, 0, 0, 0, 0, 0 };
        a[0] = z; a[1] = z;
    }

    f32x4 acc[4];
#pragma unroll
    for (int ct = 0; ct < 4; ++ct) {
        float bv = b1[ct * 16 + r];
        f32x4 c = { bv, bv, bv, bv };
        c = __builtin_amdgcn_mfma_f32_16x16x32_bf16(
                __builtin_bit_cast(bf16x8, a[0]),
                __builtin_bit_cast(bf16x8, w1f8[(ct * 2 + 0) * 64 + lane]),
                c, 0, 0, 0);
        c = __builtin_amdgcn_mfma_f32_16x16x32_bf16(
                __builtin_bit_cast(bf16x8, a[1]),
                __builtin_bit_cast(bf16x8, w1f8[(ct * 2 + 1) * 64 + lane]),
                c, 0, 0, 0);
        acc[ct] = c;
    }

#pragma unroll
    for (int ct = 0; ct < 4; ++ct)
#pragma unroll
        for (int i = 0; i < 4; ++i)
            hbuf[wv][g * 4 + i][ct * 16 + r] = fmaxf(acc[ct][i], 0.0f);

    __syncthreads();

    short8 a2[2];
#pragma unroll
    for (int kt = 0; kt < 2; ++kt) {
        const float2* hp = (const float2*)&hbuf[wv][r][kt * 32 + g * 8];
        float2 h0 = hp[0], h1 = hp[1], h2 = hp[2], h3 = hp[3];
        float hs[8] = { h0.x, h0.y, h1.x, h1.y, h2.x, h2.y, h3.x, h3.y };
        short8 t;
#pragma unroll
        for (int jj = 0; jj < 8; ++jj) t[jj] = f2bf(hs[jj]);
        a2[kt] = t;
    }

    f32x4 acc2[4];
#pragma unroll
    for (int ct = 0; ct < 4; ++ct) {
        float bv = b2[ct * 16 + r];
        f32x4 c = { bv, bv, bv, bv };
        c = __builtin_amdgcn_mfma_f32_16x16x32_bf16(
                __builtin_bit_cast(bf16x8, a2[0]),
                __builtin_bit_cast(bf16x8, w2f8[(ct * 2 + 0) * 64 + lane]),
                c, 0, 0, 0);
        c = __builtin_amdgcn_mfma_f32_16x16x32_bf16(
                __builtin_bit_cast(bf16x8, a2[1]),
                __builtin_bit_cast(bf16x8, w2f8[(ct * 2 + 1) * 64 + lane]),
                c, 0, 0, 0);
        acc2[ct] = c;
    }

#pragma unroll
    for (int ct = 0; ct < 4; ++ct)
#pragma unroll
        for (int i = 0; i < 4; ++i) {
            int nrow = row0 + g * 4 + i;
            if (nrow < N_NODES)
                neigh_out[nrow * 64 + ct * 16 + r] = acc2[ct][i];
        }
}

extern "C" void kernel_launch(void* const* d_in, const int* in_sizes, int n_in,
                              void* d_out, int out_size, void* d_ws, size_t ws_size,
                              hipStream_t stream) {
    const float* feat = (const float*)d_in[0];
    const float* W1   = (const float*)d_in[1];
    const float* b1   = (const float*)d_in[2];
    const float* W2   = (const float*)d_in[3];
    const float* b2   = (const float*)d_in[4];
    const float* eps  = (const float*)d_in[5];
    const int*   src  = (const int*)d_in[6];
    const int*   dst  = (const int*)d_in[7];
    float* out = (float*)d_out;

    char* ws = (char*)d_ws;
    short* wf = (short*)ws;                                     // 16384 B

    const size_t featbf_bytes = (size_t)N_NODES * DIM * 2;      // 12.8 MB
    const size_t hist_bytes   = (size_t)NCHUNK * NB * 4;        // 400 KB
    const size_t btot_bytes   = (size_t)NB * 4;
    const size_t edge_bytes   = (size_t)N_EDGES * 4;            // 5 MB
    const size_t need_mid  = 16384 + hist_bytes + 2 * btot_bytes + edge_bytes;
    const size_t need_full = need_mid + featbf_bytes;

    prep_w<<<32, 256, 0, stream>>>(W1, W2, wf);

    if (ws_size >= need_mid) {
        char* p = ws + 16384;
        short* featbf = nullptr;
        if (ws_size >= need_full) { featbf = (short*)p; p += featbf_bytes; }
        int* hist    = (int*)p;            p += hist_bytes;
        int* btot    = (int*)p;            p += btot_bytes;
        int* bbase   = (int*)p;            p += btot_bytes;
        int* edgebuf = (int*)p;

        if (featbf)
            conv_feat<<<3125, 256, 0, stream>>>(feat, featbf);

        hist_chunks<<<NCHUNK, 256, 0, stream>>>(dst, hist);
        scan_cols<<<(NB + 63) / 64, 64, 0, stream>>>(hist, btot);
        scan_base<<<1, 1024, 0, stream>>>(btot, bbase);
        partition_edges<<<NCHUNK, 256, 0, stream>>>(src, dst, hist, bbase, edgebuf);

        if (featbf)
            bucket_gather<1><<<NB, 512, 0, stream>>>(bbase, btot, edgebuf, featbf, out);
        else
            bucket_gather<0><<<NB, 512, 0, stream>>>(bbase, btot, edgebuf, feat, out);
    } else {
        hipMemsetAsync(d_out, 0, (size_t)N_NODES * DIM * sizeof(float), stream);
        scatter_edges<<<(N_EDGES * 16) / 256, 256, 0, stream>>>(
            (const float4*)feat, src, dst, out);
    }

    gin_mlp<<<(N_NODES + 63) / 64, 256, 0, stream>>>(feat, out, wf, b1, b2, eps);
}

// Round 4
// 108.822 us; speedup vs baseline: 5.6225x; 5.6225x over previous
//
#include <hip/hip_runtime.h>
#include <hip/hip_bf16.h>

#define N_NODES 100000
#define N_EDGES 1250000
#define DIM 64
#define NB 782            // ceil(100000/128) buckets of 128 nodes
#define NCHUNK 128
#define CHUNK 9766        // ceil(1250000/128)
#define MAXE 4096         // per-round LDS edge capacity in bucket_gather2

typedef __attribute__((ext_vector_type(8))) short short8;
typedef __attribute__((ext_vector_type(8))) __bf16 bf16x8;
typedef __attribute__((ext_vector_type(4))) float f32x4;

static __device__ __forceinline__ short f2bf(float f) {
    union { float f; unsigned u; } v; v.f = f;
    unsigned r = (v.u + 0x7fffu + ((v.u >> 16) & 1u)) >> 16;
    return (short)r;
}
static __device__ __forceinline__ float bfu2f(unsigned u) {
    union { unsigned u; float f; } v; v.u = u << 16; return v.f;
}

// ---------------- W fragment prep ----------------
__global__ __launch_bounds__(256) void prep_w(const float* __restrict__ W1,
                                              const float* __restrict__ W2,
                                              short* __restrict__ wf) {
    int idx = blockIdx.x * 256 + threadIdx.x;   // 0..8191
    int layer = idx >> 12;
    int fi = idx & 4095;
    int fragidx = fi >> 9;
    int lane = (fi >> 3) & 63;
    int jj = fi & 7;
    int ct = fragidx >> 1, kt = fragidx & 1;
    int k = kt * 32 + (lane >> 4) * 8 + jj;
    int j = ct * 16 + (lane & 15);
    const float* W = layer ? W2 : W1;
    wf[idx] = f2bf(W[k * DIM + j]);
}

// ---------------- feat f32 -> bf16 ----------------
__global__ __launch_bounds__(256) void conv_feat(const float* __restrict__ f,
                                                 short* __restrict__ o) {
    int i = (blockIdx.x * 256 + threadIdx.x) * 8;   // grid exact: 6400000/8/256=3125
    float4 a = *(const float4*)(f + i);
    float4 b = *(const float4*)(f + i + 4);
    short8 t;
    t[0] = f2bf(a.x); t[1] = f2bf(a.y); t[2] = f2bf(a.z); t[3] = f2bf(a.w);
    t[4] = f2bf(b.x); t[5] = f2bf(b.y); t[6] = f2bf(b.z); t[7] = f2bf(b.w);
    *(short8*)(o + i) = t;
}

// ---------------- bucket partition ----------------
__global__ __launch_bounds__(256) void hist_chunks(const int* __restrict__ dst,
                                                   int* __restrict__ hist) {
    __shared__ int cnt[NB];
    for (int b = threadIdx.x; b < NB; b += 256) cnt[b] = 0;
    __syncthreads();
    int c = blockIdx.x;
    int base = c * CHUNK;
    int end = base + CHUNK; if (end > N_EDGES) end = N_EDGES;
    for (int i = base + threadIdx.x; i < end; i += 256)
        atomicAdd(&cnt[dst[i] >> 7], 1);
    __syncthreads();
    for (int b = threadIdx.x; b < NB; b += 256) hist[c * NB + b] = cnt[b];
}

// per-bucket running scan over chunks: hist[c][b] -> exclusive local offset; btot[b]=total
__global__ __launch_bounds__(64) void scan_cols(int* __restrict__ hist,
                                                int* __restrict__ btot) {
    int b = blockIdx.x * 64 + threadIdx.x;
    if (b >= NB) return;
    int run = 0;
    for (int c = 0; c < NCHUNK; ++c) {
        int t = hist[c * NB + b];
        hist[c * NB + b] = run;
        run += t;
    }
    btot[b] = run;
}

__global__ __launch_bounds__(1024) void scan_base(const int* __restrict__ btot,
                                                  int* __restrict__ bbase) {
    __shared__ int s[1024];
    int t = threadIdx.x;
    int v = (t < NB) ? btot[t] : 0;
    s[t] = v; __syncthreads();
    for (int off = 1; off < 1024; off <<= 1) {
        int u = (t >= off) ? s[t - off] : 0;
        __syncthreads();
        s[t] += u;
        __syncthreads();
    }
    if (t < NB) bbase[t] = s[t] - v;    // exclusive
}

// place edges: edgebuf[pos] = src | (dst&127)<<17, grouped by bucket
__global__ __launch_bounds__(256) void partition_edges(const int* __restrict__ src,
                                                       const int* __restrict__ dst,
                                                       const int* __restrict__ hist,
                                                       const int* __restrict__ bbase,
                                                       int* __restrict__ edgebuf) {
    __shared__ int cur[NB];
    int c = blockIdx.x;
    for (int b = threadIdx.x; b < NB; b += 256)
        cur[b] = bbase[b] + hist[c * NB + b];
    __syncthreads();
    int base = c * CHUNK;
    int end = base + CHUNK; if (end > N_EDGES) end = N_EDGES;
    for (int i = base + threadIdx.x; i < end; i += 256) {
        int d = dst[i];
        int b = d >> 7;
        int p = atomicAdd(&cur[b], 1);          // LDS return-atomic
        edgebuf[p] = src[i] | ((d & 127) << 17);
    }
}

// ---------------- per-bucket gather: in-LDS counting sort + register accumulation ----------------
// BF=1: featp is bf16 (row = 128 B = 16 uint2); BF=0: f32 (row = 256 B = 16 float4).
// 512 threads: 32 node-slots x 16 feature-lanes. acc[g][4] covers node g*32+slot.
template<int BF>
__global__ __launch_bounds__(512) void bucket_gather2(const int* __restrict__ bbase,
                                                      const int* __restrict__ btot,
                                                      const int* __restrict__ edgebuf,
                                                      const void* __restrict__ featp,
                                                      float* __restrict__ neigh) {
    __shared__ int ew[MAXE];        // 16 KB raw staged words
    __shared__ int es[MAXE];        // 16 KB node-sorted srcs
    __shared__ int cnt[128];
    __shared__ int offs[128];
    __shared__ int cur[128];

    int b = blockIdx.x;
    int node0 = b << 7;
    int eb = bbase[b], ec = btot[b];
    int tid = threadIdx.x;
    int c = tid & 15;               // feature chunk
    int slot = tid >> 4;            // 0..31

    float acc[4][4];
#pragma unroll
    for (int g = 0; g < 4; ++g)
#pragma unroll
        for (int j = 0; j < 4; ++j) acc[g][j] = 0.f;

    for (int r0 = 0; r0 < ec; r0 += MAXE) {
        int n = ec - r0; if (n > MAXE) n = MAXE;

        if (tid < 128) cnt[tid] = 0;
        __syncthreads();

        // stage + per-node count
        for (int i = tid; i < n; i += 512) {
            int w = edgebuf[eb + r0 + i];
            ew[i] = w;
            atomicAdd(&cnt[(w >> 17) & 127], 1);
        }
        __syncthreads();

        // exclusive scan of cnt[128] (Hillis-Steele in offs)
        if (tid < 128) offs[tid] = cnt[tid];
        __syncthreads();
        for (int d = 1; d < 128; d <<= 1) {
            int v = 0;
            if (tid < 128 && tid >= d) v = offs[tid - d];
            __syncthreads();
            if (tid < 128 && tid >= d) offs[tid] += v;
            __syncthreads();
        }
        if (tid < 128) {
            int x = offs[tid] - cnt[tid];   // exclusive
            offs[tid] = x;
            cur[tid] = x;
        }
        __syncthreads();

        // place: es grouped by local dst
        for (int i = tid; i < n; i += 512) {
            int w = ew[i];
            int p = atomicAdd(&cur[(w >> 17) & 127], 1);
            es[p] = w & 0x1FFFF;
        }
        __syncthreads();

        // segmented register gather
#pragma unroll
        for (int g = 0; g < 4; ++g) {
            int ld = g * 32 + slot;
            int s0 = offs[ld], s1 = s0 + cnt[ld];
            int i = s0;
            for (; i + 1 < s1; i += 2) {
                int sa = es[i], sb = es[i + 1];
                if (BF) {
                    uint2 pa = ((const uint2*)featp)[sa * 16 + c];
                    uint2 pb = ((const uint2*)featp)[sb * 16 + c];
                    acc[g][0] += bfu2f(pa.x & 0xffffu) + bfu2f(pb.x & 0xffffu);
                    acc[g][1] += bfu2f(pa.x >> 16)     + bfu2f(pb.x >> 16);
                    acc[g][2] += bfu2f(pa.y & 0xffffu) + bfu2f(pb.y & 0xffffu);
                    acc[g][3] += bfu2f(pa.y >> 16)     + bfu2f(pb.y >> 16);
                } else {
                    float4 va = ((const float4*)featp)[sa * 16 + c];
                    float4 vb = ((const float4*)featp)[sb * 16 + c];
                    acc[g][0] += va.x + vb.x;
                    acc[g][1] += va.y + vb.y;
                    acc[g][2] += va.z + vb.z;
                    acc[g][3] += va.w + vb.w;
                }
            }
            if (i < s1) {
                int sa = es[i];
                if (BF) {
                    uint2 pa = ((const uint2*)featp)[sa * 16 + c];
                    acc[g][0] += bfu2f(pa.x & 0xffffu);
                    acc[g][1] += bfu2f(pa.x >> 16);
                    acc[g][2] += bfu2f(pa.y & 0xffffu);
                    acc[g][3] += bfu2f(pa.y >> 16);
                } else {
                    float4 va = ((const float4*)featp)[sa * 16 + c];
                    acc[g][0] += va.x; acc[g][1] += va.y;
                    acc[g][2] += va.z; acc[g][3] += va.w;
                }
            }
        }
        __syncthreads();    // LDS reused next round
    }

    // write out
#pragma unroll
    for (int g = 0; g < 4; ++g) {
        int nodeg = node0 + g * 32 + slot;
        if (nodeg < N_NODES) {
            float4 v = { acc[g][0], acc[g][1], acc[g][2], acc[g][3] };
            ((float4*)neigh)[nodeg * 16 + c] = v;
        }
    }
}

// ---------------- fallback atomic scatter (tiny ws) ----------------
__global__ __launch_bounds__(256) void scatter_edges(const float4* __restrict__ feat4,
                                                     const int* __restrict__ src,
                                                     const int* __restrict__ dst,
                                                     float* __restrict__ neigh) {
    int idx = blockIdx.x * 256 + threadIdx.x;
    int e = idx >> 4, c = idx & 15;
    int s = src[e], d = dst[e];
    float4 v = feat4[s * 16 + c];
    float* p = neigh + d * 64 + c * 4;
    unsafeAtomicAdd(p + 0, v.x);
    unsafeAtomicAdd(p + 1, v.y);
    unsafeAtomicAdd(p + 2, v.z);
    unsafeAtomicAdd(p + 3, v.w);
}

// ---------------- fused combine + MLP ----------------
__global__ __launch_bounds__(256) void gin_mlp(const float* __restrict__ feat,
                                               float* __restrict__ neigh_out,
                                               const short* __restrict__ wf,
                                               const float* __restrict__ b1,
                                               const float* __restrict__ b2,
                                               const float* __restrict__ epsp) {
    __shared__ float hbuf[4][16][66];

    int lane = threadIdx.x & 63;
    int wv = threadIdx.x >> 6;
    int r = lane & 15, g = lane >> 4;
    int row0 = blockIdx.x * 64 + wv * 16;
    int node = row0 + r;
    bool valid = node < N_NODES;
    float epsv = 1.0f + epsp[0];

    const short8* w1f8 = (const short8*)(wf);
    const short8* w2f8 = (const short8*)(wf + 4096);

    short8 a[2];
    if (valid) {
        const float* fp = feat + node * 64 + g * 8;
        const float* np_ = neigh_out + node * 64 + g * 8;
#pragma unroll
        for (int kt = 0; kt < 2; ++kt) {
            float4 f0 = *(const float4*)(fp + kt * 32);
            float4 f1 = *(const float4*)(fp + kt * 32 + 4);
            float4 n0 = *(const float4*)(np_ + kt * 32);
            float4 n1 = *(const float4*)(np_ + kt * 32 + 4);
            float rs[8] = { epsv * f0.x + n0.x, epsv * f0.y + n0.y,
                            epsv * f0.z + n0.z, epsv * f0.w + n0.w,
                            epsv * f1.x + n1.x, epsv * f1.y + n1.y,
                            epsv * f1.z + n1.z, epsv * f1.w + n1.w };
            short8 t;
#pragma unroll
            for (int jj = 0; jj < 8; ++jj) t[jj] = f2bf(rs[jj]);
            a[kt] = t;
        }
    } else {
        short8 z = { 0, 0, 0, 0, 0, 0, 0, 0 };
        a[0] = z; a[1] = z;
    }

    f32x4 acc[4];
#pragma unroll
    for (int ct = 0; ct < 4; ++ct) {
        float bv = b1[ct * 16 + r];
        f32x4 c = { bv, bv, bv, bv };
        c = __builtin_amdgcn_mfma_f32_16x16x32_bf16(
                __builtin_bit_cast(bf16x8, a[0]),
                __builtin_bit_cast(bf16x8, w1f8[(ct * 2 + 0) * 64 + lane]),
                c, 0, 0, 0);
        c = __builtin_amdgcn_mfma_f32_16x16x32_bf16(
                __builtin_bit_cast(bf16x8, a[1]),
                __builtin_bit_cast(bf16x8, w1f8[(ct * 2 + 1) * 64 + lane]),
                c, 0, 0, 0);
        acc[ct] = c;
    }

#pragma unroll
    for (int ct = 0; ct < 4; ++ct)
#pragma unroll
        for (int i = 0; i < 4; ++i)
            hbuf[wv][g * 4 + i][ct * 16 + r] = fmaxf(acc[ct][i], 0.0f);

    __syncthreads();

    short8 a2[2];
#pragma unroll
    for (int kt = 0; kt < 2; ++kt) {
        const float2* hp = (const float2*)&hbuf[wv][r][kt * 32 + g * 8];
        float2 h0 = hp[0], h1 = hp[1], h2 = hp[2], h3 = hp[3];
        float hs[8] = { h0.x, h0.y, h1.x, h1.y, h2.x, h2.y, h3.x, h3.y };
        short8 t;
#pragma unroll
        for (int jj = 0; jj < 8; ++jj) t[jj] = f2bf(hs[jj]);
        a2[kt] = t;
    }

    f32x4 acc2[4];
#pragma unroll
    for (int ct = 0; ct < 4; ++ct) {
        float bv = b2[ct * 16 + r];
        f32x4 c = { bv, bv, bv, bv };
        c = __builtin_amdgcn_mfma_f32_16x16x32_bf16(
                __builtin_bit_cast(bf16x8, a2[0]),
                __builtin_bit_cast(bf16x8, w2f8[(ct * 2 + 0) * 64 + lane]),
                c, 0, 0, 0);
        c = __builtin_amdgcn_mfma_f32_16x16x32_bf16(
                __builtin_bit_cast(bf16x8, a2[1]),
                __builtin_bit_cast(bf16x8, w2f8[(ct * 2 + 1) * 64 + lane]),
                c, 0, 0, 0);
        acc2[ct] = c;
    }

#pragma unroll
    for (int ct = 0; ct < 4; ++ct)
#pragma unroll
        for (int i = 0; i < 4; ++i) {
            int nrow = row0 + g * 4 + i;
            if (nrow < N_NODES)
                neigh_out[nrow * 64 + ct * 16 + r] = acc2[ct][i];
        }
}

extern "C" void kernel_launch(void* const* d_in, const int* in_sizes, int n_in,
                              void* d_out, int out_size, void* d_ws, size_t ws_size,
                              hipStream_t stream) {
    const float* feat = (const float*)d_in[0];
    const float* W1   = (const float*)d_in[1];
    const float* b1   = (const float*)d_in[2];
    const float* W2   = (const float*)d_in[3];
    const float* b2   = (const float*)d_in[4];
    const float* eps  = (const float*)d_in[5];
    const int*   src  = (const int*)d_in[6];
    const int*   dst  = (const int*)d_in[7];
    float* out = (float*)d_out;

    char* ws = (char*)d_ws;
    short* wf = (short*)ws;                                     // 16384 B

    const size_t featbf_bytes = (size_t)N_NODES * DIM * 2;      // 12.8 MB
    const size_t hist_bytes   = (size_t)NCHUNK * NB * 4;        // 400 KB
    const size_t btot_bytes   = (size_t)NB * 4;
    const size_t edge_bytes   = (size_t)N_EDGES * 4;            // 5 MB
    const size_t need_mid  = 16384 + hist_bytes + 2 * btot_bytes + edge_bytes;
    const size_t need_full = need_mid + featbf_bytes;

    prep_w<<<32, 256, 0, stream>>>(W1, W2, wf);

    if (ws_size >= need_mid) {
        char* p = ws + 16384;
        short* featbf = nullptr;
        if (ws_size >= need_full) { featbf = (short*)p; p += featbf_bytes; }
        int* hist    = (int*)p;            p += hist_bytes;
        int* btot    = (int*)p;            p += btot_bytes;
        int* bbase   = (int*)p;            p += btot_bytes;
        int* edgebuf = (int*)p;

        if (featbf)
            conv_feat<<<3125, 256, 0, stream>>>(feat, featbf);

        hist_chunks<<<NCHUNK, 256, 0, stream>>>(dst, hist);
        scan_cols<<<(NB + 63) / 64, 64, 0, stream>>>(hist, btot);
        scan_base<<<1, 1024, 0, stream>>>(btot, bbase);
        partition_edges<<<NCHUNK, 256, 0, stream>>>(src, dst, hist, bbase, edgebuf);

        if (featbf)
            bucket_gather2<1><<<NB, 512, 0, stream>>>(bbase, btot, edgebuf, featbf, out);
        else
            bucket_gather2<0><<<NB, 512, 0, stream>>>(bbase, btot, edgebuf, feat, out);
    } else {
        hipMemsetAsync(d_out, 0, (size_t)N_NODES * DIM * sizeof(float), stream);
        scatter_edges<<<(N_EDGES * 16) / 256, 256, 0, stream>>>(
            (const float4*)feat, src, dst, out);
    }

    gin_mlp<<<(N_NODES + 63) / 64, 256, 0, stream>>>(feat, out, wf, b1, b2, eps);
}